// Round 7
// baseline (799.760 us; speedup 1.0000x reference)
//
#include <hip/hip_runtime.h>
#include <math.h>

// ---------------------------------------------------------------------------
// SiReN loss on MI355X — round 7: remove cnorm payload from CSR.
// k_scatter writes ONLY csrc (halves random-write line traffic);
// k_gather computes norm = dinv[src]*dinv[node] on the fly.
// ---------------------------------------------------------------------------

__global__ void k_count(const int* __restrict__ dst, int* __restrict__ deg, int NE) {
  int e = blockIdx.x * blockDim.x + threadIdx.x;
  if (e < NE) atomicAdd(&deg[dst[e]], 1);
}

__global__ void k_scan1(const int* __restrict__ deg, int* __restrict__ bsum, int NN) {
  __shared__ int sm[256];
  int t = threadIdx.x;
  int i = blockIdx.x * 256 + t;
  sm[t] = (i < NN) ? deg[i] : 0;
  __syncthreads();
  for (int s = 128; s > 0; s >>= 1) {
    if (t < s) sm[t] += sm[t + s];
    __syncthreads();
  }
  if (t == 0) bsum[blockIdx.x] = sm[0];
}

__global__ void k_scan2(int* __restrict__ bsum, int nb) {
  __shared__ int sm[1024];
  int t = threadIdx.x;
  int v = (t < nb) ? bsum[t] : 0;
  sm[t] = v;
  __syncthreads();
  for (int off = 1; off < 1024; off <<= 1) {
    int add = (t >= off) ? sm[t - off] : 0;
    __syncthreads();
    sm[t] += add;
    __syncthreads();
  }
  if (t < nb) bsum[t] = sm[t] - v;  // exclusive
}

__global__ void k_scan3(const int* __restrict__ deg, const int* __restrict__ bsum,
                        int* __restrict__ rowptr, int NN) {
  __shared__ int sm[256];
  int t = threadIdx.x;
  int i = blockIdx.x * 256 + t;
  int v = (i < NN) ? deg[i] : 0;
  sm[t] = v;
  __syncthreads();
  for (int off = 1; off < 256; off <<= 1) {
    int add = (t >= off) ? sm[t - off] : 0;
    __syncthreads();
    sm[t] += add;
    __syncthreads();
  }
  int incl = sm[t] + bsum[blockIdx.x];
  if (i < NN) rowptr[i] = incl - v;
  if (i == NN - 1) rowptr[NN] = incl;
}

__global__ void k_dinv(const int* __restrict__ deg, float* __restrict__ dinv, int NN) {
  int i = blockIdx.x * blockDim.x + threadIdx.x;
  if (i < NN) {
    int d = deg[i];
    dinv[i] = (d > 0) ? rsqrtf((float)d) : 0.f;
  }
}

// scatter ONLY the src index (4B per edge)
__global__ void k_scatter(const int* __restrict__ src, const int* __restrict__ dst,
                          const int* __restrict__ rowptr, int* __restrict__ cursor,
                          int* __restrict__ csrc, int NE) {
  int e = blockIdx.x * blockDim.x + threadIdx.x;
  if (e >= NE) return;
  int s = src[e], d = dst[e];
  int pos = rowptr[d] + atomicAdd(&cursor[d], 1);
  csrc[pos] = s;
}

// 16-lane sub-group per node, lane = 4 dims (float4); 4 nodes per wave
// norm computed on the fly from dinv
__global__ __launch_bounds__(256) void k_gather(const float* __restrict__ x,
                                                const int* __restrict__ rowptr,
                                                const int* __restrict__ csrc,
                                                const float* __restrict__ dinv,
                                                float* __restrict__ out, int NN) {
  int gid = blockIdx.x * blockDim.x + threadIdx.x;
  int node = gid >> 4;
  if (node >= NN) return;
  int sl = gid & 15;
  int beg = rowptr[node], end = rowptr[node + 1];
  float dn = dinv[node];
  float ax = 0.f, ay = 0.f, az = 0.f, aw = 0.f;
  int i = beg;
  for (; i + 1 < end; i += 2) {
    int s0 = csrc[i], s1 = csrc[i + 1];
    float n0 = dinv[s0], n1 = dinv[s1];
    float4 x0 = *(const float4*)&x[(size_t)s0 * 64 + sl * 4];
    float4 x1 = *(const float4*)&x[(size_t)s1 * 64 + sl * 4];
    ax += n0 * x0.x; ay += n0 * x0.y; az += n0 * x0.z; aw += n0 * x0.w;
    ax += n1 * x1.x; ay += n1 * x1.y; az += n1 * x1.z; aw += n1 * x1.w;
  }
  if (i < end) {
    int s0 = csrc[i];
    float n0 = dinv[s0];
    float4 x0 = *(const float4*)&x[(size_t)s0 * 64 + sl * 4];
    ax += n0 * x0.x; ay += n0 * x0.y; az += n0 * x0.z; aw += n0 * x0.w;
  }
  float4 r; r.x = ax * dn; r.y = ay * dn; r.z = az * dn; r.w = aw * dn;
  *(float4*)&out[(size_t)node * 64 + sl * 4] = r;
}

// ---------------------------------------------------------------------------
// k_node: one 64-node tile per block; 4x4 register tiling; ONE weight
// buffer re-staged W0 -> W1 -> AW (k-major, stride 66); shfl reductions.
// ---------------------------------------------------------------------------
#define TS 66

__device__ inline float fast_tanh(float x) {
  float t = __expf(fminf(fmaxf(2.f * x, -30.f), 30.f));
  return (t - 1.f) / (t + 1.f);
}

__global__ __launch_bounds__(256, 4) void k_node(const float* __restrict__ E,
                                                 const float* __restrict__ E2,
                                                 const float* __restrict__ Wm,
                                                 const float* __restrict__ bm,
                                                 const float* __restrict__ AW,
                                                 const float* __restrict__ ab,
                                                 const float* __restrict__ qw,
                                                 float* __restrict__ b1buf,
                                                 const float* __restrict__ b2buf,
                                                 int NN) {
  __shared__ float Wl[64 * TS];     // current weight, k-major: Wl[k*TS + col]
  __shared__ float TA[64 * TS];     // E2 tile -> ZN tile (node-major)
  __shared__ float TB[64 * TS];     // H tile  -> ZP tile (node-major)
  __shared__ float b0s[64], b1s[64], abs_[64], qs[64];

  int tid = threadIdx.x;
  int tx = tid & 15, ty = tid >> 4;        // ty 0..15
  int lrow = tid >> 2;                     // staging row 0..63
  int lcol = (tid & 3) * 16;               // staging col base
  int node0 = blockIdx.x * 64;
  int snode = node0 + lrow;
  bool sok = snode < NN;

  for (int idx = tid; idx < 4096; idx += 256) {
    int j = idx >> 6, k = idx & 63;
    Wl[k * TS + j] = Wm[idx];
  }
  if (tid < 64) { b0s[tid] = bm[tid]; b1s[tid] = bm[64 + tid]; abs_[tid] = ab[tid]; qs[tid] = qw[tid]; }
  {
    const float4 z4 = make_float4(0.f, 0.f, 0.f, 0.f);
    const float* sp = E2 + (size_t)snode * 64 + lcol;
#pragma unroll
    for (int c = 0; c < 4; ++c) {
      float4 xv = sok ? *(const float4*)(sp + 4 * c) : z4;
      float2* wp = (float2*)&TA[lrow * TS + lcol + 4 * c];
      wp[0] = make_float2(xv.x, xv.y);
      wp[1] = make_float2(xv.z, xv.w);
    }
  }
  __syncthreads();

  // GEMM1: acc = E2 @ W0^T + b0
  float acc[4][4];
#pragma unroll
  for (int a = 0; a < 4; ++a)
#pragma unroll
    for (int b = 0; b < 4; ++b) acc[a][b] = b0s[tx + 16 * b];
#pragma unroll 4
  for (int k = 0; k < 64; ++k) {
    float xv[4], wv[4];
#pragma unroll
    for (int a = 0; a < 4; ++a) xv[a] = TA[(ty + 16 * a) * TS + k];
#pragma unroll
    for (int b = 0; b < 4; ++b) wv[b] = Wl[k * TS + tx + 16 * b];
#pragma unroll
    for (int a = 0; a < 4; ++a)
#pragma unroll
      for (int b = 0; b < 4; ++b) acc[a][b] += xv[a] * wv[b];
  }
  __syncthreads();   // Wl (W0) reads done

  // re-stage Wl = W1; write H = relu(acc) into TB
  for (int idx = tid; idx < 4096; idx += 256) {
    int j = idx >> 6, k = idx & 63;
    Wl[k * TS + j] = Wm[4096 + idx];
  }
#pragma unroll
  for (int a = 0; a < 4; ++a)
#pragma unroll
    for (int b = 0; b < 4; ++b)
      TB[(ty + 16 * a) * TS + tx + 16 * b] = fmaxf(acc[a][b], 0.f);
  __syncthreads();

  // GEMM2: acc = H @ W1^T + b1
#pragma unroll
  for (int a = 0; a < 4; ++a)
#pragma unroll
    for (int b = 0; b < 4; ++b) acc[a][b] = b1s[tx + 16 * b];
#pragma unroll 4
  for (int k = 0; k < 64; ++k) {
    float xv[4], wv[4];
#pragma unroll
    for (int a = 0; a < 4; ++a) xv[a] = TB[(ty + 16 * a) * TS + k];
#pragma unroll
    for (int b = 0; b < 4; ++b) wv[b] = Wl[k * TS + tx + 16 * b];
#pragma unroll
    for (int a = 0; a < 4; ++a)
#pragma unroll
      for (int b = 0; b < 4; ++b) acc[a][b] += xv[a] * wv[b];
  }
  __syncthreads();   // Wl (W1) + TB (H) reads done

  // re-stage Wl = AW; ZN = relu(acc) -> TA; ZP = (E+b1+b2)/3 -> TB
  for (int idx = tid; idx < 4096; idx += 256) {
    int j = idx >> 6, k = idx & 63;
    Wl[k * TS + j] = AW[idx];
  }
#pragma unroll
  for (int a = 0; a < 4; ++a)
#pragma unroll
    for (int b = 0; b < 4; ++b)
      TA[(ty + 16 * a) * TS + tx + 16 * b] = fmaxf(acc[a][b], 0.f);
  {
    const float4 z4 = make_float4(0.f, 0.f, 0.f, 0.f);
    const float* pe = E + (size_t)snode * 64 + lcol;
    const float* p1 = b1buf + (size_t)snode * 64 + lcol;
    const float* p2 = b2buf + (size_t)snode * 64 + lcol;
#pragma unroll
    for (int c = 0; c < 4; ++c) {
      float4 e4 = sok ? *(const float4*)(pe + 4 * c) : z4;
      float4 a4 = sok ? *(const float4*)(p1 + 4 * c) : z4;
      float4 c4 = sok ? *(const float4*)(p2 + 4 * c) : z4;
      float2* wp = (float2*)&TB[lrow * TS + lcol + 4 * c];
      wp[0] = make_float2((e4.x + a4.x + c4.x) * (1.f / 3.f),
                          (e4.y + a4.y + c4.y) * (1.f / 3.f));
      wp[1] = make_float2((e4.z + a4.z + c4.z) * (1.f / 3.f),
                          (e4.w + a4.w + c4.w) * (1.f / 3.f));
    }
  }
  __syncthreads();

  // Attention GEMMs: ac1 = ZP@AW^T+ab (TB), ac2 = ZN@AW^T+ab (TA)
  float ac1[4][4], ac2[4][4];
#pragma unroll
  for (int a = 0; a < 4; ++a)
#pragma unroll
    for (int b = 0; b < 4; ++b) { ac1[a][b] = abs_[tx + 16 * b]; ac2[a][b] = ac1[a][b]; }
#pragma unroll 4
  for (int k = 0; k < 64; ++k) {
    float zp[4], zn[4], wv[4];
#pragma unroll
    for (int a = 0; a < 4; ++a) {
      zp[a] = TB[(ty + 16 * a) * TS + k];
      zn[a] = TA[(ty + 16 * a) * TS + k];
    }
#pragma unroll
    for (int b = 0; b < 4; ++b) wv[b] = Wl[k * TS + tx + 16 * b];
#pragma unroll
    for (int a = 0; a < 4; ++a)
#pragma unroll
      for (int b = 0; b < 4; ++b) {
        ac1[a][b] += zp[a] * wv[b];
        ac2[a][b] += zn[a] * wv[b];
      }
  }

  // per-node q-dots of tanh + 16-lane shfl reduce (tx-lanes are consecutive)
  float a0v[4], a1v[4];
#pragma unroll
  for (int a = 0; a < 4; ++a) {
    float p1 = 0.f, p2 = 0.f;
#pragma unroll
    for (int b = 0; b < 4; ++b) {
      float q = qs[tx + 16 * b];
      p1 += fast_tanh(ac1[a][b]) * q;
      p2 += fast_tanh(ac2[a][b]) * q;
    }
#pragma unroll
    for (int off = 8; off; off >>= 1) {
      p1 += __shfl_xor(p1, off);
      p2 += __shfl_xor(p2, off);
    }
    float m = fmaxf(p1, p2);
    float e1 = __expf(p1 - m), e2 = __expf(p2 - m);
    float inv = 1.f / (e1 + e2);
    a0v[a] = e1 * inv;
    a1v[a] = e2 * inv;
  }

  // epilogue: Z = a0*ZP + a1*ZN directly to global
#pragma unroll
  for (int a = 0; a < 4; ++a) {
    int node = node0 + ty + 16 * a;
    if (node < NN) {
      float* op = b1buf + (size_t)node * 64;
#pragma unroll
      for (int b = 0; b < 4; ++b) {
        int col = tx + 16 * b;
        int base = (ty + 16 * a) * TS + col;
        op[col] = a0v[a] * TB[base] + a1v[a] * TA[base];
      }
    }
  }
}

// 16-lane sub-group per batch element; block handles 16; grid = ceil(B/16)
__global__ __launch_bounds__(256) void k_score(const float* __restrict__ Z,
                                               const int* __restrict__ u,
                                               const int* __restrict__ v,
                                               const int* __restrict__ n,
                                               const float* __restrict__ w,
                                               float* __restrict__ out, int B, int K) {
  __shared__ float xbuf[16][65];   // K <= 64
  __shared__ float part[16];
  int t = threadIdx.x;
  int wv = t >> 6, lane = t & 63;
  int sg = lane >> 4, sl = lane & 15;
  int bloc = wv * 4 + sg;
  int b = blockIdx.x * 16 + bloc;
  float lossb = 0.f;
  if (b < B) {
    int uid = u[b], vid = v[b];
    float4 u4 = *(const float4*)&Z[(size_t)uid * 64 + sl * 4];
    float4 v4 = *(const float4*)&Z[(size_t)vid * 64 + sl * 4];
    float p = u4.x * v4.x + u4.y * v4.y + u4.z * v4.z + u4.w * v4.w;
#pragma unroll
    for (int off = 8; off; off >>= 1) p += __shfl_xor(p, off);
    float wb = w[b];
    float sgn = (wb > 0.f) ? 1.f : ((wb < 0.f) ? -1.f : 0.f);
    float sp = sgn * p;
    float regl = u4.x * u4.x + u4.y * u4.y + u4.z * u4.z + u4.w * u4.w
               + v4.x * v4.x + v4.y * v4.y + v4.z * v4.z + v4.w * v4.w;
    const int* nb_ = n + (size_t)b * K;
    for (int k = 0; k < K; ++k) {
      int nid = nb_[k];
      float4 n4 = *(const float4*)&Z[(size_t)nid * 64 + sl * 4];
      float d = u4.x * n4.x + u4.y * n4.y + u4.z * n4.z + u4.w * n4.w;
      regl += n4.x * n4.x + n4.y * n4.y + n4.z * n4.z + n4.w * n4.w;
#pragma unroll
      for (int off = 8; off; off >>= 1) d += __shfl_xor(d, off);
      if (sl == 0) xbuf[bloc][k] = sp - d;
    }
#pragma unroll
    for (int off = 8; off; off >>= 1) regl += __shfl_xor(regl, off);
    float sb = 0.f;
    for (int k = sl; k < K; k += 16) {
      float x = xbuf[bloc][k];
      sb += fminf(x, 0.f) - log1pf(expf(-fabsf(x)));
    }
#pragma unroll
    for (int off = 8; off; off >>= 1) sb += __shfl_xor(sb, off);
    lossb = -sb + 1e-4f * regl;
  }
  if (sl == 0) part[bloc] = (b < B) ? lossb : 0.f;
  __syncthreads();
  if (t == 0) {
    float s = 0.f;
#pragma unroll
    for (int i = 0; i < 16; ++i) s += part[i];
    unsafeAtomicAdd(out, s);
  }
}

extern "C" void kernel_launch(void* const* d_in, const int* in_sizes, int n_in,
                              void* d_out, int out_size, void* d_ws, size_t ws_size,
                              hipStream_t stream) {
  const float* E  = (const float*)d_in[0];
  const float* E2 = (const float*)d_in[1];
  const float* Wm = (const float*)d_in[2];
  const float* bm = (const float*)d_in[3];
  const float* AW = (const float*)d_in[4];
  const float* ab = (const float*)d_in[5];
  const float* qw = (const float*)d_in[6];
  const int*   ei = (const int*)d_in[7];
  const int*   u  = (const int*)d_in[8];
  const int*   v  = (const int*)d_in[9];
  const int*   nn = (const int*)d_in[10];
  const float* w  = (const float*)d_in[11];

  const int NN = in_sizes[0] / 64;        // 150000
  const int NE = in_sizes[7] / 2;         // 3200000
  const int B  = in_sizes[8];             // 16384
  const int K  = in_sizes[10] / B;        // 40

  const int* src = ei;
  const int* dst = ei + NE;

  // workspace layout
  float* ws     = (float*)d_ws;
  float* dinv   = ws;                         // NN floats
  float* b1     = dinv + NN;                  // NN*64
  float* b2     = b1 + (size_t)NN * 64;       // NN*64
  int*   deg_i  = (int*)(b2 + (size_t)NN * 64);   // NN ints
  int*   cursor = deg_i + NN;                 // NN ints
  int*   rowptr = cursor + NN;                // NN+1 ints
  int*   bsum   = rowptr + NN + 1;            // <=1024 ints
  int*   csrc   = bsum + 1024;                // NE ints
  float* outf   = (float*)d_out;

  const int nb = (NN + 255) / 256;            // scan blocks (<=1024)

  hipMemsetAsync(deg_i, 0, (size_t)2 * NN * sizeof(int), stream);
  hipMemsetAsync(outf, 0, sizeof(float), stream);

  k_count<<<(NE + 255) / 256, 256, 0, stream>>>(dst, deg_i, NE);
  k_scan1<<<nb, 256, 0, stream>>>(deg_i, bsum, NN);
  k_scan2<<<1, 1024, 0, stream>>>(bsum, nb);
  k_scan3<<<nb, 256, 0, stream>>>(deg_i, bsum, rowptr, NN);
  k_dinv<<<(NN + 255) / 256, 256, 0, stream>>>(deg_i, dinv, NN);
  k_scatter<<<(NE + 255) / 256, 256, 0, stream>>>(src, dst, rowptr, cursor, csrc, NE);

  int gatherBlocks = ((size_t)NN * 16 + 255) / 256;   // 16 lanes per node
  k_gather<<<gatherBlocks, 256, 0, stream>>>(E, rowptr, csrc, dinv, b1, NN);
  k_gather<<<gatherBlocks, 256, 0, stream>>>(b1, rowptr, csrc, dinv, b2, NN);

  int nodeTiles = (NN + 63) / 64;
  k_node<<<nodeTiles, 256, 0, stream>>>(E, E2, Wm, bm, AW, ab, qw, b1, b2, NN);

  k_score<<<(B + 15) / 16, 256, 0, stream>>>(b1, u, v, nn, w, outf, B, K);
}

// Round 8
// 762.179 us; speedup vs baseline: 1.0493x; 1.0493x over previous
//
#include <hip/hip_runtime.h>
#include <math.h>

// ---------------------------------------------------------------------------
// SiReN loss on MI355X — round 8: XCD-partitioned count/scatter.
// blockIdx%8 -> node-range partition so each XCD's scatter writes stay in its
// own L2 (1.6MB window), killing the 16x dirty-line amplification.
// ---------------------------------------------------------------------------

#define NXCD 8

// group r counts only dst in [NN*r/8, NN*(r+1)/8); grid-strides whole edge list
__global__ void k_count(const int* __restrict__ dst, int* __restrict__ deg,
                        int NE, int NN) {
  int grp = blockIdx.x & (NXCD - 1);
  int lo = (int)((long)NN * grp / NXCD);
  int hi = (int)((long)NN * (grp + 1) / NXCD);
  int nb = gridDim.x >> 3;            // blocks per group
  int bi = blockIdx.x >> 3;           // block index within group
  int stride = nb * blockDim.x;
  for (int e = bi * blockDim.x + threadIdx.x; e < NE; e += stride) {
    int d = dst[e];
    if (d >= lo && d < hi) atomicAdd(&deg[d], 1);
  }
}

__global__ void k_scan1(const int* __restrict__ deg, int* __restrict__ bsum, int NN) {
  __shared__ int sm[256];
  int t = threadIdx.x;
  int i = blockIdx.x * 256 + t;
  sm[t] = (i < NN) ? deg[i] : 0;
  __syncthreads();
  for (int s = 128; s > 0; s >>= 1) {
    if (t < s) sm[t] += sm[t + s];
    __syncthreads();
  }
  if (t == 0) bsum[blockIdx.x] = sm[0];
}

__global__ void k_scan2(int* __restrict__ bsum, int nb) {
  __shared__ int sm[1024];
  int t = threadIdx.x;
  int v = (t < nb) ? bsum[t] : 0;
  sm[t] = v;
  __syncthreads();
  for (int off = 1; off < 1024; off <<= 1) {
    int add = (t >= off) ? sm[t - off] : 0;
    __syncthreads();
    sm[t] += add;
    __syncthreads();
  }
  if (t < nb) bsum[t] = sm[t] - v;  // exclusive
}

__global__ void k_scan3(const int* __restrict__ deg, const int* __restrict__ bsum,
                        int* __restrict__ rowptr, int NN) {
  __shared__ int sm[256];
  int t = threadIdx.x;
  int i = blockIdx.x * 256 + t;
  int v = (i < NN) ? deg[i] : 0;
  sm[t] = v;
  __syncthreads();
  for (int off = 1; off < 256; off <<= 1) {
    int add = (t >= off) ? sm[t - off] : 0;
    __syncthreads();
    sm[t] += add;
    __syncthreads();
  }
  int incl = sm[t] + bsum[blockIdx.x];
  if (i < NN) rowptr[i] = incl - v;
  if (i == NN - 1) rowptr[NN] = incl;
}

__global__ void k_dinv(const int* __restrict__ deg, float* __restrict__ dinv, int NN) {
  int i = blockIdx.x * blockDim.x + threadIdx.x;
  if (i < NN) {
    int d = deg[i];
    dinv[i] = (d > 0) ? rsqrtf((float)d) : 0.f;
  }
}

// group r scatters only edges whose dst is in its node range (L2-local writes)
__global__ void k_scatter(const int* __restrict__ src, const int* __restrict__ dst,
                          const int* __restrict__ rowptr, int* __restrict__ cursor,
                          int* __restrict__ csrc, int NE, int NN) {
  int grp = blockIdx.x & (NXCD - 1);
  int lo = (int)((long)NN * grp / NXCD);
  int hi = (int)((long)NN * (grp + 1) / NXCD);
  int nb = gridDim.x >> 3;
  int bi = blockIdx.x >> 3;
  int stride = nb * blockDim.x;
  for (int e = bi * blockDim.x + threadIdx.x; e < NE; e += stride) {
    int d = dst[e];
    if (d >= lo && d < hi) {
      int pos = rowptr[d] + atomicAdd(&cursor[d], 1);
      csrc[pos] = src[e];
    }
  }
}

// 16-lane sub-group per node, lane = 4 dims (float4); 4 nodes per wave
__global__ __launch_bounds__(256) void k_gather(const float* __restrict__ x,
                                                const int* __restrict__ rowptr,
                                                const int* __restrict__ csrc,
                                                const float* __restrict__ dinv,
                                                float* __restrict__ out, int NN) {
  int gid = blockIdx.x * blockDim.x + threadIdx.x;
  int node = gid >> 4;
  if (node >= NN) return;
  int sl = gid & 15;
  int beg = rowptr[node], end = rowptr[node + 1];
  float dn = dinv[node];
  float ax = 0.f, ay = 0.f, az = 0.f, aw = 0.f;
  int i = beg;
  for (; i + 1 < end; i += 2) {
    int s0 = csrc[i], s1 = csrc[i + 1];
    float n0 = dinv[s0], n1 = dinv[s1];
    float4 x0 = *(const float4*)&x[(size_t)s0 * 64 + sl * 4];
    float4 x1 = *(const float4*)&x[(size_t)s1 * 64 + sl * 4];
    ax += n0 * x0.x; ay += n0 * x0.y; az += n0 * x0.z; aw += n0 * x0.w;
    ax += n1 * x1.x; ay += n1 * x1.y; az += n1 * x1.z; aw += n1 * x1.w;
  }
  if (i < end) {
    int s0 = csrc[i];
    float n0 = dinv[s0];
    float4 x0 = *(const float4*)&x[(size_t)s0 * 64 + sl * 4];
    ax += n0 * x0.x; ay += n0 * x0.y; az += n0 * x0.z; aw += n0 * x0.w;
  }
  float4 r; r.x = ax * dn; r.y = ay * dn; r.z = az * dn; r.w = aw * dn;
  *(float4*)&out[(size_t)node * 64 + sl * 4] = r;
}

// ---------------------------------------------------------------------------
// k_node: one 64-node tile per block; 4x4 register tiling; ONE weight
// buffer re-staged W0 -> W1 -> AW (k-major, stride 66); shfl reductions.
// ---------------------------------------------------------------------------
#define TS 66

__device__ inline float fast_tanh(float x) {
  float t = __expf(fminf(fmaxf(2.f * x, -30.f), 30.f));
  return (t - 1.f) / (t + 1.f);
}

__global__ __launch_bounds__(256, 4) void k_node(const float* __restrict__ E,
                                                 const float* __restrict__ E2,
                                                 const float* __restrict__ Wm,
                                                 const float* __restrict__ bm,
                                                 const float* __restrict__ AW,
                                                 const float* __restrict__ ab,
                                                 const float* __restrict__ qw,
                                                 float* __restrict__ b1buf,
                                                 const float* __restrict__ b2buf,
                                                 int NN) {
  __shared__ float Wl[64 * TS];     // current weight, k-major: Wl[k*TS + col]
  __shared__ float TA[64 * TS];     // E2 tile -> ZN tile (node-major)
  __shared__ float TB[64 * TS];     // H tile  -> ZP tile (node-major)
  __shared__ float b0s[64], b1s[64], abs_[64], qs[64];

  int tid = threadIdx.x;
  int tx = tid & 15, ty = tid >> 4;        // ty 0..15
  int lrow = tid >> 2;                     // staging row 0..63
  int lcol = (tid & 3) * 16;               // staging col base
  int node0 = blockIdx.x * 64;
  int snode = node0 + lrow;
  bool sok = snode < NN;

  for (int idx = tid; idx < 4096; idx += 256) {
    int j = idx >> 6, k = idx & 63;
    Wl[k * TS + j] = Wm[idx];
  }
  if (tid < 64) { b0s[tid] = bm[tid]; b1s[tid] = bm[64 + tid]; abs_[tid] = ab[tid]; qs[tid] = qw[tid]; }
  {
    const float4 z4 = make_float4(0.f, 0.f, 0.f, 0.f);
    const float* sp = E2 + (size_t)snode * 64 + lcol;
#pragma unroll
    for (int c = 0; c < 4; ++c) {
      float4 xv = sok ? *(const float4*)(sp + 4 * c) : z4;
      float2* wp = (float2*)&TA[lrow * TS + lcol + 4 * c];
      wp[0] = make_float2(xv.x, xv.y);
      wp[1] = make_float2(xv.z, xv.w);
    }
  }
  __syncthreads();

  // GEMM1: acc = E2 @ W0^T + b0
  float acc[4][4];
#pragma unroll
  for (int a = 0; a < 4; ++a)
#pragma unroll
    for (int b = 0; b < 4; ++b) acc[a][b] = b0s[tx + 16 * b];
#pragma unroll 4
  for (int k = 0; k < 64; ++k) {
    float xv[4], wv[4];
#pragma unroll
    for (int a = 0; a < 4; ++a) xv[a] = TA[(ty + 16 * a) * TS + k];
#pragma unroll
    for (int b = 0; b < 4; ++b) wv[b] = Wl[k * TS + tx + 16 * b];
#pragma unroll
    for (int a = 0; a < 4; ++a)
#pragma unroll
      for (int b = 0; b < 4; ++b) acc[a][b] += xv[a] * wv[b];
  }
  __syncthreads();   // Wl (W0) reads done

  // re-stage Wl = W1; write H = relu(acc) into TB
  for (int idx = tid; idx < 4096; idx += 256) {
    int j = idx >> 6, k = idx & 63;
    Wl[k * TS + j] = Wm[4096 + idx];
  }
#pragma unroll
  for (int a = 0; a < 4; ++a)
#pragma unroll
    for (int b = 0; b < 4; ++b)
      TB[(ty + 16 * a) * TS + tx + 16 * b] = fmaxf(acc[a][b], 0.f);
  __syncthreads();

  // GEMM2: acc = H @ W1^T + b1
#pragma unroll
  for (int a = 0; a < 4; ++a)
#pragma unroll
    for (int b = 0; b < 4; ++b) acc[a][b] = b1s[tx + 16 * b];
#pragma unroll 4
  for (int k = 0; k < 64; ++k) {
    float xv[4], wv[4];
#pragma unroll
    for (int a = 0; a < 4; ++a) xv[a] = TB[(ty + 16 * a) * TS + k];
#pragma unroll
    for (int b = 0; b < 4; ++b) wv[b] = Wl[k * TS + tx + 16 * b];
#pragma unroll
    for (int a = 0; a < 4; ++a)
#pragma unroll
      for (int b = 0; b < 4; ++b) acc[a][b] += xv[a] * wv[b];
  }
  __syncthreads();   // Wl (W1) + TB (H) reads done

  // re-stage Wl = AW; ZN = relu(acc) -> TA; ZP = (E+b1+b2)/3 -> TB
  for (int idx = tid; idx < 4096; idx += 256) {
    int j = idx >> 6, k = idx & 63;
    Wl[k * TS + j] = AW[idx];
  }
#pragma unroll
  for (int a = 0; a < 4; ++a)
#pragma unroll
    for (int b = 0; b < 4; ++b)
      TA[(ty + 16 * a) * TS + tx + 16 * b] = fmaxf(acc[a][b], 0.f);
  {
    const float4 z4 = make_float4(0.f, 0.f, 0.f, 0.f);
    const float* pe = E + (size_t)snode * 64 + lcol;
    const float* p1 = b1buf + (size_t)snode * 64 + lcol;
    const float* p2 = b2buf + (size_t)snode * 64 + lcol;
#pragma unroll
    for (int c = 0; c < 4; ++c) {
      float4 e4 = sok ? *(const float4*)(pe + 4 * c) : z4;
      float4 a4 = sok ? *(const float4*)(p1 + 4 * c) : z4;
      float4 c4 = sok ? *(const float4*)(p2 + 4 * c) : z4;
      float2* wp = (float2*)&TB[lrow * TS + lcol + 4 * c];
      wp[0] = make_float2((e4.x + a4.x + c4.x) * (1.f / 3.f),
                          (e4.y + a4.y + c4.y) * (1.f / 3.f));
      wp[1] = make_float2((e4.z + a4.z + c4.z) * (1.f / 3.f),
                          (e4.w + a4.w + c4.w) * (1.f / 3.f));
    }
  }
  __syncthreads();

  // Attention GEMMs: ac1 = ZP@AW^T+ab (TB), ac2 = ZN@AW^T+ab (TA)
  float ac1[4][4], ac2[4][4];
#pragma unroll
  for (int a = 0; a < 4; ++a)
#pragma unroll
    for (int b = 0; b < 4; ++b) { ac1[a][b] = abs_[tx + 16 * b]; ac2[a][b] = ac1[a][b]; }
#pragma unroll 4
  for (int k = 0; k < 64; ++k) {
    float zp[4], zn[4], wv[4];
#pragma unroll
    for (int a = 0; a < 4; ++a) {
      zp[a] = TB[(ty + 16 * a) * TS + k];
      zn[a] = TA[(ty + 16 * a) * TS + k];
    }
#pragma unroll
    for (int b = 0; b < 4; ++b) wv[b] = Wl[k * TS + tx + 16 * b];
#pragma unroll
    for (int a = 0; a < 4; ++a)
#pragma unroll
      for (int b = 0; b < 4; ++b) {
        ac1[a][b] += zp[a] * wv[b];
        ac2[a][b] += zn[a] * wv[b];
      }
  }

  // per-node q-dots of tanh + 16-lane shfl reduce (tx-lanes are consecutive)
  float a0v[4], a1v[4];
#pragma unroll
  for (int a = 0; a < 4; ++a) {
    float p1 = 0.f, p2 = 0.f;
#pragma unroll
    for (int b = 0; b < 4; ++b) {
      float q = qs[tx + 16 * b];
      p1 += fast_tanh(ac1[a][b]) * q;
      p2 += fast_tanh(ac2[a][b]) * q;
    }
#pragma unroll
    for (int off = 8; off; off >>= 1) {
      p1 += __shfl_xor(p1, off);
      p2 += __shfl_xor(p2, off);
    }
    float m = fmaxf(p1, p2);
    float e1 = __expf(p1 - m), e2 = __expf(p2 - m);
    float inv = 1.f / (e1 + e2);
    a0v[a] = e1 * inv;
    a1v[a] = e2 * inv;
  }

  // epilogue: Z = a0*ZP + a1*ZN directly to global
#pragma unroll
  for (int a = 0; a < 4; ++a) {
    int node = node0 + ty + 16 * a;
    if (node < NN) {
      float* op = b1buf + (size_t)node * 64;
#pragma unroll
      for (int b = 0; b < 4; ++b) {
        int col = tx + 16 * b;
        int base = (ty + 16 * a) * TS + col;
        op[col] = a0v[a] * TB[base] + a1v[a] * TA[base];
      }
    }
  }
}

// 16-lane sub-group per batch element; block handles 16; grid = ceil(B/16)
__global__ __launch_bounds__(256) void k_score(const float* __restrict__ Z,
                                               const int* __restrict__ u,
                                               const int* __restrict__ v,
                                               const int* __restrict__ n,
                                               const float* __restrict__ w,
                                               float* __restrict__ out, int B, int K) {
  __shared__ float xbuf[16][65];   // K <= 64
  __shared__ float part[16];
  int t = threadIdx.x;
  int wv = t >> 6, lane = t & 63;
  int sg = lane >> 4, sl = lane & 15;
  int bloc = wv * 4 + sg;
  int b = blockIdx.x * 16 + bloc;
  float lossb = 0.f;
  if (b < B) {
    int uid = u[b], vid = v[b];
    float4 u4 = *(const float4*)&Z[(size_t)uid * 64 + sl * 4];
    float4 v4 = *(const float4*)&Z[(size_t)vid * 64 + sl * 4];
    float p = u4.x * v4.x + u4.y * v4.y + u4.z * v4.z + u4.w * v4.w;
#pragma unroll
    for (int off = 8; off; off >>= 1) p += __shfl_xor(p, off);
    float wb = w[b];
    float sgn = (wb > 0.f) ? 1.f : ((wb < 0.f) ? -1.f : 0.f);
    float sp = sgn * p;
    float regl = u4.x * u4.x + u4.y * u4.y + u4.z * u4.z + u4.w * u4.w
               + v4.x * v4.x + v4.y * v4.y + v4.z * v4.z + v4.w * v4.w;
    const int* nb_ = n + (size_t)b * K;
    for (int k = 0; k < K; ++k) {
      int nid = nb_[k];
      float4 n4 = *(const float4*)&Z[(size_t)nid * 64 + sl * 4];
      float d = u4.x * n4.x + u4.y * n4.y + u4.z * n4.z + u4.w * n4.w;
      regl += n4.x * n4.x + n4.y * n4.y + n4.z * n4.z + n4.w * n4.w;
#pragma unroll
      for (int off = 8; off; off >>= 1) d += __shfl_xor(d, off);
      if (sl == 0) xbuf[bloc][k] = sp - d;
    }
#pragma unroll
    for (int off = 8; off; off >>= 1) regl += __shfl_xor(regl, off);
    float sb = 0.f;
    for (int k = sl; k < K; k += 16) {
      float x = xbuf[bloc][k];
      sb += fminf(x, 0.f) - log1pf(expf(-fabsf(x)));
    }
#pragma unroll
    for (int off = 8; off; off >>= 1) sb += __shfl_xor(sb, off);
    lossb = -sb + 1e-4f * regl;
  }
  if (sl == 0) part[bloc] = (b < B) ? lossb : 0.f;
  __syncthreads();
  if (t == 0) {
    float s = 0.f;
#pragma unroll
    for (int i = 0; i < 16; ++i) s += part[i];
    unsafeAtomicAdd(out, s);
  }
}

extern "C" void kernel_launch(void* const* d_in, const int* in_sizes, int n_in,
                              void* d_out, int out_size, void* d_ws, size_t ws_size,
                              hipStream_t stream) {
  const float* E  = (const float*)d_in[0];
  const float* E2 = (const float*)d_in[1];
  const float* Wm = (const float*)d_in[2];
  const float* bm = (const float*)d_in[3];
  const float* AW = (const float*)d_in[4];
  const float* ab = (const float*)d_in[5];
  const float* qw = (const float*)d_in[6];
  const int*   ei = (const int*)d_in[7];
  const int*   u  = (const int*)d_in[8];
  const int*   v  = (const int*)d_in[9];
  const int*   nn = (const int*)d_in[10];
  const float* w  = (const float*)d_in[11];

  const int NN = in_sizes[0] / 64;        // 150000
  const int NE = in_sizes[7] / 2;         // 3200000
  const int B  = in_sizes[8];             // 16384
  const int K  = in_sizes[10] / B;        // 40

  const int* src = ei;
  const int* dst = ei + NE;

  // workspace layout
  float* ws     = (float*)d_ws;
  float* dinv   = ws;                         // NN floats
  float* b1     = dinv + NN;                  // NN*64
  float* b2     = b1 + (size_t)NN * 64;       // NN*64
  int*   deg_i  = (int*)(b2 + (size_t)NN * 64);   // NN ints
  int*   cursor = deg_i + NN;                 // NN ints
  int*   rowptr = cursor + NN;                // NN+1 ints
  int*   bsum   = rowptr + NN + 1;            // <=1024 ints
  int*   csrc   = bsum + 1024;                // NE ints
  float* outf   = (float*)d_out;

  const int nb = (NN + 255) / 256;            // scan blocks (<=1024)

  hipMemsetAsync(deg_i, 0, (size_t)2 * NN * sizeof(int), stream);
  hipMemsetAsync(outf, 0, sizeof(float), stream);

  k_count<<<2048, 256, 0, stream>>>(dst, deg_i, NE, NN);
  k_scan1<<<nb, 256, 0, stream>>>(deg_i, bsum, NN);
  k_scan2<<<1, 1024, 0, stream>>>(bsum, nb);
  k_scan3<<<nb, 256, 0, stream>>>(deg_i, bsum, rowptr, NN);
  k_dinv<<<(NN + 255) / 256, 256, 0, stream>>>(deg_i, dinv, NN);
  k_scatter<<<2048, 256, 0, stream>>>(src, dst, rowptr, cursor, csrc, NE, NN);

  int gatherBlocks = ((size_t)NN * 16 + 255) / 256;   // 16 lanes per node
  k_gather<<<gatherBlocks, 256, 0, stream>>>(E, rowptr, csrc, dinv, b1, NN);
  k_gather<<<gatherBlocks, 256, 0, stream>>>(b1, rowptr, csrc, dinv, b2, NN);

  int nodeTiles = (NN + 63) / 64;
  k_node<<<nodeTiles, 256, 0, stream>>>(E, E2, Wm, bm, AW, ab, qw, b1, b2, NN);

  k_score<<<(B + 15) / 16, 256, 0, stream>>>(b1, u, v, nn, w, outf, B, K);
}

// Round 9
// 647.216 us; speedup vs baseline: 1.2357x; 1.1776x over previous
//
#include <hip/hip_runtime.h>
#include <math.h>

// ---------------------------------------------------------------------------
// SiReN loss on MI355X — round 9:
//  * k_count fuses rank assignment (rank[e] = fetch_add) -> k_scatter is
//    ATOMIC-FREE (atomics proved memory-side on MI355X; halve their count).
//  * k_node LDS stride 66 -> 65 (staging-write bank conflict 4-way -> 2-way).
// Workspace: [dinv NN][b1 NN*64][b2 NN*64][deg NN][rowptr NN+1][bsum 1024]
//            [csrc NE][rank NE]
// ---------------------------------------------------------------------------

// count + per-edge rank within its dst bucket (arrival order)
__global__ void k_count(const int* __restrict__ dst, int* __restrict__ deg,
                        int* __restrict__ rank, int NE) {
  int e = blockIdx.x * blockDim.x + threadIdx.x;
  if (e < NE) rank[e] = atomicAdd(&deg[dst[e]], 1);
}

__global__ void k_scan1(const int* __restrict__ deg, int* __restrict__ bsum, int NN) {
  __shared__ int sm[256];
  int t = threadIdx.x;
  int i = blockIdx.x * 256 + t;
  sm[t] = (i < NN) ? deg[i] : 0;
  __syncthreads();
  for (int s = 128; s > 0; s >>= 1) {
    if (t < s) sm[t] += sm[t + s];
    __syncthreads();
  }
  if (t == 0) bsum[blockIdx.x] = sm[0];
}

__global__ void k_scan2(int* __restrict__ bsum, int nb) {
  __shared__ int sm[1024];
  int t = threadIdx.x;
  int v = (t < nb) ? bsum[t] : 0;
  sm[t] = v;
  __syncthreads();
  for (int off = 1; off < 1024; off <<= 1) {
    int add = (t >= off) ? sm[t - off] : 0;
    __syncthreads();
    sm[t] += add;
    __syncthreads();
  }
  if (t < nb) bsum[t] = sm[t] - v;  // exclusive
}

__global__ void k_scan3(const int* __restrict__ deg, const int* __restrict__ bsum,
                        int* __restrict__ rowptr, int NN) {
  __shared__ int sm[256];
  int t = threadIdx.x;
  int i = blockIdx.x * 256 + t;
  int v = (i < NN) ? deg[i] : 0;
  sm[t] = v;
  __syncthreads();
  for (int off = 1; off < 256; off <<= 1) {
    int add = (t >= off) ? sm[t - off] : 0;
    __syncthreads();
    sm[t] += add;
    __syncthreads();
  }
  int incl = sm[t] + bsum[blockIdx.x];
  if (i < NN) rowptr[i] = incl - v;
  if (i == NN - 1) rowptr[NN] = incl;
}

__global__ void k_dinv(const int* __restrict__ deg, float* __restrict__ dinv, int NN) {
  int i = blockIdx.x * blockDim.x + threadIdx.x;
  if (i < NN) {
    int d = deg[i];
    dinv[i] = (d > 0) ? rsqrtf((float)d) : 0.f;
  }
}

// atomic-free scatter: pos = rowptr[dst] + rank
__global__ void k_scatter(const int* __restrict__ src, const int* __restrict__ dst,
                          const int* __restrict__ rowptr, const int* __restrict__ rank,
                          int* __restrict__ csrc, int NE) {
  int e = blockIdx.x * blockDim.x + threadIdx.x;
  if (e >= NE) return;
  int d = dst[e];
  csrc[rowptr[d] + rank[e]] = src[e];
}

// 16-lane sub-group per node, lane = 4 dims (float4); 4 nodes per wave
__global__ __launch_bounds__(256) void k_gather(const float* __restrict__ x,
                                                const int* __restrict__ rowptr,
                                                const int* __restrict__ csrc,
                                                const float* __restrict__ dinv,
                                                float* __restrict__ out, int NN) {
  int gid = blockIdx.x * blockDim.x + threadIdx.x;
  int node = gid >> 4;
  if (node >= NN) return;
  int sl = gid & 15;
  int beg = rowptr[node], end = rowptr[node + 1];
  float dn = dinv[node];
  float ax = 0.f, ay = 0.f, az = 0.f, aw = 0.f;
  int i = beg;
  for (; i + 1 < end; i += 2) {
    int s0 = csrc[i], s1 = csrc[i + 1];
    float n0 = dinv[s0], n1 = dinv[s1];
    float4 x0 = *(const float4*)&x[(size_t)s0 * 64 + sl * 4];
    float4 x1 = *(const float4*)&x[(size_t)s1 * 64 + sl * 4];
    ax += n0 * x0.x; ay += n0 * x0.y; az += n0 * x0.z; aw += n0 * x0.w;
    ax += n1 * x1.x; ay += n1 * x1.y; az += n1 * x1.z; aw += n1 * x1.w;
  }
  if (i < end) {
    int s0 = csrc[i];
    float n0 = dinv[s0];
    float4 x0 = *(const float4*)&x[(size_t)s0 * 64 + sl * 4];
    ax += n0 * x0.x; ay += n0 * x0.y; az += n0 * x0.z; aw += n0 * x0.w;
  }
  float4 r; r.x = ax * dn; r.y = ay * dn; r.z = az * dn; r.w = aw * dn;
  *(float4*)&out[(size_t)node * 64 + sl * 4] = r;
}

// ---------------------------------------------------------------------------
// k_node: one 64-node tile per block; 4x4 register tiling; ONE weight
// buffer re-staged W0 -> W1 -> AW (k-major); shfl reductions.
// TS=65: staging writes lane*65 mod 32 -> 2-way (was 4-way at 66).
// ---------------------------------------------------------------------------
#define TS 65

__device__ inline float fast_tanh(float x) {
  float t = __expf(fminf(fmaxf(2.f * x, -30.f), 30.f));
  return (t - 1.f) / (t + 1.f);
}

__global__ __launch_bounds__(256, 4) void k_node(const float* __restrict__ E,
                                                 const float* __restrict__ E2,
                                                 const float* __restrict__ Wm,
                                                 const float* __restrict__ bm,
                                                 const float* __restrict__ AW,
                                                 const float* __restrict__ ab,
                                                 const float* __restrict__ qw,
                                                 float* __restrict__ b1buf,
                                                 const float* __restrict__ b2buf,
                                                 int NN) {
  __shared__ float Wl[64 * TS];     // current weight, k-major: Wl[k*TS + col]
  __shared__ float TA[64 * TS];     // E2 tile -> ZN tile (node-major)
  __shared__ float TB[64 * TS];     // H tile  -> ZP tile (node-major)
  __shared__ float b0s[64], b1s[64], abs_[64], qs[64];

  int tid = threadIdx.x;
  int tx = tid & 15, ty = tid >> 4;        // ty 0..15
  int lrow = tid >> 2;                     // staging row 0..63
  int lcol = (tid & 3) * 16;               // staging col base
  int node0 = blockIdx.x * 64;
  int snode = node0 + lrow;
  bool sok = snode < NN;

  for (int idx = tid; idx < 4096; idx += 256) {
    int j = idx >> 6, k = idx & 63;
    Wl[k * TS + j] = Wm[idx];
  }
  if (tid < 64) { b0s[tid] = bm[tid]; b1s[tid] = bm[64 + tid]; abs_[tid] = ab[tid]; qs[tid] = qw[tid]; }
  {
    const float4 z4 = make_float4(0.f, 0.f, 0.f, 0.f);
    const float* sp = E2 + (size_t)snode * 64 + lcol;
#pragma unroll
    for (int c = 0; c < 4; ++c) {
      float4 xv = sok ? *(const float4*)(sp + 4 * c) : z4;
      float2* wp = (float2*)&TA[lrow * TS + lcol + 4 * c];
      wp[0] = make_float2(xv.x, xv.y);
      wp[1] = make_float2(xv.z, xv.w);
    }
  }
  __syncthreads();

  // GEMM1: acc = E2 @ W0^T + b0
  float acc[4][4];
#pragma unroll
  for (int a = 0; a < 4; ++a)
#pragma unroll
    for (int b = 0; b < 4; ++b) acc[a][b] = b0s[tx + 16 * b];
#pragma unroll 4
  for (int k = 0; k < 64; ++k) {
    float xv[4], wv[4];
#pragma unroll
    for (int a = 0; a < 4; ++a) xv[a] = TA[(ty + 16 * a) * TS + k];
#pragma unroll
    for (int b = 0; b < 4; ++b) wv[b] = Wl[k * TS + tx + 16 * b];
#pragma unroll
    for (int a = 0; a < 4; ++a)
#pragma unroll
      for (int b = 0; b < 4; ++b) acc[a][b] += xv[a] * wv[b];
  }
  __syncthreads();   // Wl (W0) reads done

  // re-stage Wl = W1; write H = relu(acc) into TB
  for (int idx = tid; idx < 4096; idx += 256) {
    int j = idx >> 6, k = idx & 63;
    Wl[k * TS + j] = Wm[4096 + idx];
  }
#pragma unroll
  for (int a = 0; a < 4; ++a)
#pragma unroll
    for (int b = 0; b < 4; ++b)
      TB[(ty + 16 * a) * TS + tx + 16 * b] = fmaxf(acc[a][b], 0.f);
  __syncthreads();

  // GEMM2: acc = H @ W1^T + b1
#pragma unroll
  for (int a = 0; a < 4; ++a)
#pragma unroll
    for (int b = 0; b < 4; ++b) acc[a][b] = b1s[tx + 16 * b];
#pragma unroll 4
  for (int k = 0; k < 64; ++k) {
    float xv[4], wv[4];
#pragma unroll
    for (int a = 0; a < 4; ++a) xv[a] = TB[(ty + 16 * a) * TS + k];
#pragma unroll
    for (int b = 0; b < 4; ++b) wv[b] = Wl[k * TS + tx + 16 * b];
#pragma unroll
    for (int a = 0; a < 4; ++a)
#pragma unroll
      for (int b = 0; b < 4; ++b) acc[a][b] += xv[a] * wv[b];
  }
  __syncthreads();   // Wl (W1) + TB (H) reads done

  // re-stage Wl = AW; ZN = relu(acc) -> TA; ZP = (E+b1+b2)/3 -> TB
  for (int idx = tid; idx < 4096; idx += 256) {
    int j = idx >> 6, k = idx & 63;
    Wl[k * TS + j] = AW[idx];
  }
#pragma unroll
  for (int a = 0; a < 4; ++a)
#pragma unroll
    for (int b = 0; b < 4; ++b)
      TA[(ty + 16 * a) * TS + tx + 16 * b] = fmaxf(acc[a][b], 0.f);
  {
    const float4 z4 = make_float4(0.f, 0.f, 0.f, 0.f);
    const float* pe = E + (size_t)snode * 64 + lcol;
    const float* p1 = b1buf + (size_t)snode * 64 + lcol;
    const float* p2 = b2buf + (size_t)snode * 64 + lcol;
#pragma unroll
    for (int c = 0; c < 4; ++c) {
      float4 e4 = sok ? *(const float4*)(pe + 4 * c) : z4;
      float4 a4 = sok ? *(const float4*)(p1 + 4 * c) : z4;
      float4 c4 = sok ? *(const float4*)(p2 + 4 * c) : z4;
      float2* wp = (float2*)&TB[lrow * TS + lcol + 4 * c];
      wp[0] = make_float2((e4.x + a4.x + c4.x) * (1.f / 3.f),
                          (e4.y + a4.y + c4.y) * (1.f / 3.f));
      wp[1] = make_float2((e4.z + a4.z + c4.z) * (1.f / 3.f),
                          (e4.w + a4.w + c4.w) * (1.f / 3.f));
    }
  }
  __syncthreads();

  // Attention GEMMs: ac1 = ZP@AW^T+ab (TB), ac2 = ZN@AW^T+ab (TA)
  float ac1[4][4], ac2[4][4];
#pragma unroll
  for (int a = 0; a < 4; ++a)
#pragma unroll
    for (int b = 0; b < 4; ++b) { ac1[a][b] = abs_[tx + 16 * b]; ac2[a][b] = ac1[a][b]; }
#pragma unroll 4
  for (int k = 0; k < 64; ++k) {
    float zp[4], zn[4], wv[4];
#pragma unroll
    for (int a = 0; a < 4; ++a) {
      zp[a] = TB[(ty + 16 * a) * TS + k];
      zn[a] = TA[(ty + 16 * a) * TS + k];
    }
#pragma unroll
    for (int b = 0; b < 4; ++b) wv[b] = Wl[k * TS + tx + 16 * b];
#pragma unroll
    for (int a = 0; a < 4; ++a)
#pragma unroll
      for (int b = 0; b < 4; ++b) {
        ac1[a][b] += zp[a] * wv[b];
        ac2[a][b] += zn[a] * wv[b];
      }
  }

  // per-node q-dots of tanh + 16-lane shfl reduce (tx-lanes are consecutive)
  float a0v[4], a1v[4];
#pragma unroll
  for (int a = 0; a < 4; ++a) {
    float p1 = 0.f, p2 = 0.f;
#pragma unroll
    for (int b = 0; b < 4; ++b) {
      float q = qs[tx + 16 * b];
      p1 += fast_tanh(ac1[a][b]) * q;
      p2 += fast_tanh(ac2[a][b]) * q;
    }
#pragma unroll
    for (int off = 8; off; off >>= 1) {
      p1 += __shfl_xor(p1, off);
      p2 += __shfl_xor(p2, off);
    }
    float m = fmaxf(p1, p2);
    float e1 = __expf(p1 - m), e2 = __expf(p2 - m);
    float inv = 1.f / (e1 + e2);
    a0v[a] = e1 * inv;
    a1v[a] = e2 * inv;
  }

  // epilogue: Z = a0*ZP + a1*ZN directly to global
#pragma unroll
  for (int a = 0; a < 4; ++a) {
    int node = node0 + ty + 16 * a;
    if (node < NN) {
      float* op = b1buf + (size_t)node * 64;
#pragma unroll
      for (int b = 0; b < 4; ++b) {
        int col = tx + 16 * b;
        int base = (ty + 16 * a) * TS + col;
        op[col] = a0v[a] * TB[base] + a1v[a] * TA[base];
      }
    }
  }
}

// 16-lane sub-group per batch element; block handles 16; grid = ceil(B/16)
__global__ __launch_bounds__(256) void k_score(const float* __restrict__ Z,
                                               const int* __restrict__ u,
                                               const int* __restrict__ v,
                                               const int* __restrict__ n,
                                               const float* __restrict__ w,
                                               float* __restrict__ out, int B, int K) {
  __shared__ float xbuf[16][65];   // K <= 64
  __shared__ float part[16];
  int t = threadIdx.x;
  int wv = t >> 6, lane = t & 63;
  int sg = lane >> 4, sl = lane & 15;
  int bloc = wv * 4 + sg;
  int b = blockIdx.x * 16 + bloc;
  float lossb = 0.f;
  if (b < B) {
    int uid = u[b], vid = v[b];
    float4 u4 = *(const float4*)&Z[(size_t)uid * 64 + sl * 4];
    float4 v4 = *(const float4*)&Z[(size_t)vid * 64 + sl * 4];
    float p = u4.x * v4.x + u4.y * v4.y + u4.z * v4.z + u4.w * v4.w;
#pragma unroll
    for (int off = 8; off; off >>= 1) p += __shfl_xor(p, off);
    float wb = w[b];
    float sgn = (wb > 0.f) ? 1.f : ((wb < 0.f) ? -1.f : 0.f);
    float sp = sgn * p;
    float regl = u4.x * u4.x + u4.y * u4.y + u4.z * u4.z + u4.w * u4.w
               + v4.x * v4.x + v4.y * v4.y + v4.z * v4.z + v4.w * v4.w;
    const int* nb_ = n + (size_t)b * K;
    for (int k = 0; k < K; ++k) {
      int nid = nb_[k];
      float4 n4 = *(const float4*)&Z[(size_t)nid * 64 + sl * 4];
      float d = u4.x * n4.x + u4.y * n4.y + u4.z * n4.z + u4.w * n4.w;
      regl += n4.x * n4.x + n4.y * n4.y + n4.z * n4.z + n4.w * n4.w;
#pragma unroll
      for (int off = 8; off; off >>= 1) d += __shfl_xor(d, off);
      if (sl == 0) xbuf[bloc][k] = sp - d;
    }
#pragma unroll
    for (int off = 8; off; off >>= 1) regl += __shfl_xor(regl, off);
    float sb = 0.f;
    for (int k = sl; k < K; k += 16) {
      float x = xbuf[bloc][k];
      sb += fminf(x, 0.f) - log1pf(expf(-fabsf(x)));
    }
#pragma unroll
    for (int off = 8; off; off >>= 1) sb += __shfl_xor(sb, off);
    lossb = -sb + 1e-4f * regl;
  }
  if (sl == 0) part[bloc] = (b < B) ? lossb : 0.f;
  __syncthreads();
  if (t == 0) {
    float s = 0.f;
#pragma unroll
    for (int i = 0; i < 16; ++i) s += part[i];
    unsafeAtomicAdd(out, s);
  }
}

extern "C" void kernel_launch(void* const* d_in, const int* in_sizes, int n_in,
                              void* d_out, int out_size, void* d_ws, size_t ws_size,
                              hipStream_t stream) {
  const float* E  = (const float*)d_in[0];
  const float* E2 = (const float*)d_in[1];
  const float* Wm = (const float*)d_in[2];
  const float* bm = (const float*)d_in[3];
  const float* AW = (const float*)d_in[4];
  const float* ab = (const float*)d_in[5];
  const float* qw = (const float*)d_in[6];
  const int*   ei = (const int*)d_in[7];
  const int*   u  = (const int*)d_in[8];
  const int*   v  = (const int*)d_in[9];
  const int*   nn = (const int*)d_in[10];
  const float* w  = (const float*)d_in[11];

  const int NN = in_sizes[0] / 64;        // 150000
  const int NE = in_sizes[7] / 2;         // 3200000
  const int B  = in_sizes[8];             // 16384
  const int K  = in_sizes[10] / B;        // 40

  const int* src = ei;
  const int* dst = ei + NE;

  // workspace layout
  float* ws     = (float*)d_ws;
  float* dinv   = ws;                         // NN floats
  float* b1     = dinv + NN;                  // NN*64
  float* b2     = b1 + (size_t)NN * 64;       // NN*64
  int*   deg_i  = (int*)(b2 + (size_t)NN * 64);   // NN ints
  int*   rowptr = deg_i + NN;                 // NN+1 ints
  int*   bsum   = rowptr + NN + 1;            // <=1024 ints
  int*   csrc   = bsum + 1024;                // NE ints
  int*   rank   = csrc + NE;                  // NE ints
  float* outf   = (float*)d_out;

  const int nb = (NN + 255) / 256;            // scan blocks (<=1024)

  hipMemsetAsync(deg_i, 0, (size_t)NN * sizeof(int), stream);
  hipMemsetAsync(outf, 0, sizeof(float), stream);

  k_count<<<(NE + 255) / 256, 256, 0, stream>>>(dst, deg_i, rank, NE);
  k_scan1<<<nb, 256, 0, stream>>>(deg_i, bsum, NN);
  k_scan2<<<1, 1024, 0, stream>>>(bsum, nb);
  k_scan3<<<nb, 256, 0, stream>>>(deg_i, bsum, rowptr, NN);
  k_dinv<<<(NN + 255) / 256, 256, 0, stream>>>(deg_i, dinv, NN);
  k_scatter<<<(NE + 255) / 256, 256, 0, stream>>>(src, dst, rowptr, rank, csrc, NE);

  int gatherBlocks = ((size_t)NN * 16 + 255) / 256;   // 16 lanes per node
  k_gather<<<gatherBlocks, 256, 0, stream>>>(E, rowptr, csrc, dinv, b1, NN);
  k_gather<<<gatherBlocks, 256, 0, stream>>>(b1, rowptr, csrc, dinv, b2, NN);

  int nodeTiles = (NN + 63) / 64;
  k_node<<<nodeTiles, 256, 0, stream>>>(E, E2, Wm, bm, AW, ab, qw, b1, b2, NN);

  k_score<<<(B + 15) / 16, 256, 0, stream>>>(b1, u, v, nn, w, outf, B, K);
}